// Round 1
// baseline (325.811 us; speedup 1.0000x reference)
//
#include <hip/hip_runtime.h>

#define B_SZ  4096
#define IN_F  512
#define OUT_F 512
#define NC    64
#define PAIRS (OUT_F * NC)   // 32768
#define TOT   (IN_F * OUT_F * NC)

// ---------------------------------------------------------------------------
// K1: fused c_sum[o,n] = sum_i (mean + eps*exp(0.5*lv))  and
//     kl = 0.5 * sum (exp(lv) + mean^2 - 1 - lv)
// Layout: arrays are (IN, OUT, NC), NC fastest -> idx = i*PAIRS + (o*NC + n).
// Thread handles 4 consecutive (o,n) pairs (float4); blocks split the i-range
// into 32 chunks of 16; partial sums combined via atomicAdd (32-way contention
// per address, negligible). Pure HBM-bound: 201 MB.
// ---------------------------------------------------------------------------
__global__ __launch_bounds__(256)
void k1_csum_kl(const float* __restrict__ cm,
                const float* __restrict__ clv,
                const float* __restrict__ eps,
                float* __restrict__ csum,
                float* __restrict__ kl_out,
                int S) {
    const int CH   = 32;           // i-chunks
    const int ILEN = IN_F / CH;    // 16
    int pb = blockIdx.x / CH;      // 0..31 (pair blocks of 1024 pairs)
    int ch = blockIdx.x % CH;
    int pair4 = pb * 1024 + threadIdx.x * 4;

    float sx = 0.f, sy = 0.f, sz = 0.f, sw = 0.f;
    float klp = 0.f;
    int i0 = ch * ILEN;

    for (int i = i0; i < i0 + ILEN; ++i) {
        int idx = i * PAIRS + pair4;
        float4 m  = *(const float4*)(cm  + idx);
        float4 lv = *(const float4*)(clv + idx);
        // eps summed over samples (S==1 here)
        float4 es = *(const float4*)(eps + idx);
        for (int si = 1; si < S; ++si) {
            float4 e2 = *(const float4*)(eps + si * TOT + idx);
            es.x += e2.x; es.y += e2.y; es.z += e2.z; es.w += e2.w;
        }
        float e1x = __expf(0.5f * lv.x);
        float e1y = __expf(0.5f * lv.y);
        float e1z = __expf(0.5f * lv.z);
        float e1w = __expf(0.5f * lv.w);
        sx += (float)S * m.x + es.x * e1x;
        sy += (float)S * m.y + es.y * e1y;
        sz += (float)S * m.z + es.z * e1z;
        sw += (float)S * m.w + es.w * e1w;
        // var = exp(lv) = e1*e1 (one expf instead of two)
        klp += (e1x*e1x + m.x*m.x - 1.f - lv.x);
        klp += (e1y*e1y + m.y*m.y - 1.f - lv.y);
        klp += (e1z*e1z + m.z*m.z - 1.f - lv.z);
        klp += (e1w*e1w + m.w*m.w - 1.f - lv.w);
    }

    atomicAdd(&csum[pair4 + 0], sx);
    atomicAdd(&csum[pair4 + 1], sy);
    atomicAdd(&csum[pair4 + 2], sz);
    atomicAdd(&csum[pair4 + 3], sw);

    // KL: wave shuffle reduce -> LDS -> one atomic per block
    for (int off = 32; off; off >>= 1)
        klp += __shfl_down(klp, off, 64);
    __shared__ float wsum[4];
    if ((threadIdx.x & 63) == 0) wsum[threadIdx.x >> 6] = klp;
    __syncthreads();
    if (threadIdx.x == 0) {
        float t = wsum[0] + wsum[1] + wsum[2] + wsum[3];
        atomicAdd(kl_out, 0.5f * t);
    }
}

// ---------------------------------------------------------------------------
// K2: rbf[b,n] = exp(-dist_sq(b,n) / (2*sigma_n^2 + 1e-8))
// One block per b. x row staged in LDS; thread (n = t>>2, c = t&3) covers a
// 128-wide i-chunk; 4 partials combined with shfl_xor (lanes n*4..n*4+3 are
// adjacent in the wave). centers (128 KB) stays L2-resident across blocks.
// ---------------------------------------------------------------------------
__global__ __launch_bounds__(256)
void k2_rbf(const float* __restrict__ x,
            const float* __restrict__ centers,
            const float* __restrict__ log_sigma,
            float* __restrict__ rbf) {
    __shared__ float xs[IN_F];
    int b = blockIdx.x;
    int t = threadIdx.x;
    if (t < 128)
        *(float4*)(xs + t * 4) = *(const float4*)(x + b * IN_F + t * 4);
    __syncthreads();

    int n = t >> 2, c = t & 3;
    const float* cp = centers + n * IN_F + c * 128;
    const float* xp = xs + c * 128;
    float d = 0.f;
#pragma unroll 8
    for (int j = 0; j < 128; j += 4) {
        float4 cv = *(const float4*)(cp + j);
        float4 xv = *(const float4*)(xp + j);
        float dx = xv.x - cv.x, dy = xv.y - cv.y;
        float dz = xv.z - cv.z, dw = xv.w - cv.w;
        d += dx*dx + dy*dy + dz*dz + dw*dw;
    }
    d += __shfl_xor(d, 1, 64);
    d += __shfl_xor(d, 2, 64);
    if (c == 0) {
        float sg  = __expf(log_sigma[n]);
        float inv = 1.f / (2.f * sg * sg + 1e-8f);
        rbf[b * NC + n] = __expf(-d * inv);
    }
}

// ---------------------------------------------------------------------------
// K3: out[b,o] = sum_i x[b,i]*W[i,o] + (1/S) * sum_n rbf[b,n]*csum[o,n]
// Treated as one GEMM with K = 512 + 64. 64x64 tile per block, 256 threads,
// 4x4 accumulator per thread. LDS tiles stored [k][m]/[k][n] so the inner
// loop is 2x ds_read_b128 + 16 FMA per k. Row stride 68 keeps 16B alignment
// and <=2-way bank aliasing on staging writes (2-way is free on gfx950).
// ---------------------------------------------------------------------------
__global__ __launch_bounds__(256)
void k3_out(const float* __restrict__ x,
            const float* __restrict__ bw,
            const float* __restrict__ rbf,
            const float* __restrict__ csum,
            float* __restrict__ out,
            float inv_S) {
    __shared__ float As[16][68];
    __shared__ float Bs[16][68];

    int t = threadIdx.x;
    int btile = blockIdx.x / (OUT_F / 64);
    int otile = blockIdx.x % (OUT_F / 64);
    int b0 = btile * 64, o0 = otile * 64;
    int tx = t & 15, ty = t >> 4;       // compute mapping: col group / row group
    int r  = t >> 2, c4 = t & 3;        // A-staging: row 0..63, k-group 0..3
    int r2 = t >> 4, c2 = t & 15;       // B-staging: k 0..15, col group 0..15

    float acc[4][4] = {};

    // ---- main K: x @ base_weight ----
    for (int kt = 0; kt < IN_F / 16; ++kt) {
        float4 xa = *(const float4*)(x  + (b0 + r) * IN_F + kt * 16 + c4 * 4);
        float4 wb = *(const float4*)(bw + (kt * 16 + r2) * OUT_F + o0 + c2 * 4);
        __syncthreads();
        As[c4 * 4 + 0][r] = xa.x;
        As[c4 * 4 + 1][r] = xa.y;
        As[c4 * 4 + 2][r] = xa.z;
        As[c4 * 4 + 3][r] = xa.w;
        *(float4*)&Bs[r2][c2 * 4] = wb;
        __syncthreads();
#pragma unroll
        for (int k = 0; k < 16; ++k) {
            float4 av = *(float4*)&As[k][ty * 4];
            float4 bv = *(float4*)&Bs[k][tx * 4];
            acc[0][0] += av.x * bv.x; acc[0][1] += av.x * bv.y;
            acc[0][2] += av.x * bv.z; acc[0][3] += av.x * bv.w;
            acc[1][0] += av.y * bv.x; acc[1][1] += av.y * bv.y;
            acc[1][2] += av.y * bv.z; acc[1][3] += av.y * bv.w;
            acc[2][0] += av.z * bv.x; acc[2][1] += av.z * bv.y;
            acc[2][2] += av.z * bv.z; acc[2][3] += av.z * bv.w;
            acc[3][0] += av.w * bv.x; acc[3][1] += av.w * bv.y;
            acc[3][2] += av.w * bv.z; acc[3][3] += av.w * bv.w;
        }
    }

    // ---- rbf K: rbf @ csum^T (csum stored [o][n], so transpose-stage) ----
    for (int kt2 = 0; kt2 < NC / 16; ++kt2) {
        float4 ra = *(const float4*)(rbf  + (b0 + r) * NC + kt2 * 16 + c4 * 4);
        float4 cs = *(const float4*)(csum + (o0 + r) * NC + kt2 * 16 + c4 * 4);
        __syncthreads();
        As[c4 * 4 + 0][r] = ra.x;
        As[c4 * 4 + 1][r] = ra.y;
        As[c4 * 4 + 2][r] = ra.z;
        As[c4 * 4 + 3][r] = ra.w;
        Bs[c4 * 4 + 0][r] = cs.x * inv_S;
        Bs[c4 * 4 + 1][r] = cs.y * inv_S;
        Bs[c4 * 4 + 2][r] = cs.z * inv_S;
        Bs[c4 * 4 + 3][r] = cs.w * inv_S;
        __syncthreads();
#pragma unroll
        for (int k = 0; k < 16; ++k) {
            float4 av = *(float4*)&As[k][ty * 4];
            float4 bv = *(float4*)&Bs[k][tx * 4];
            acc[0][0] += av.x * bv.x; acc[0][1] += av.x * bv.y;
            acc[0][2] += av.x * bv.z; acc[0][3] += av.x * bv.w;
            acc[1][0] += av.y * bv.x; acc[1][1] += av.y * bv.y;
            acc[1][2] += av.y * bv.z; acc[1][3] += av.y * bv.w;
            acc[2][0] += av.z * bv.x; acc[2][1] += av.z * bv.y;
            acc[2][2] += av.z * bv.z; acc[2][3] += av.z * bv.w;
            acc[3][0] += av.w * bv.x; acc[3][1] += av.w * bv.y;
            acc[3][2] += av.w * bv.z; acc[3][3] += av.w * bv.w;
        }
    }

#pragma unroll
    for (int i = 0; i < 4; ++i) {
        float4 v = { acc[i][0], acc[i][1], acc[i][2], acc[i][3] };
        *(float4*)(out + (b0 + ty * 4 + i) * OUT_F + o0 + tx * 4) = v;
    }
}

// ---------------------------------------------------------------------------
extern "C" void kernel_launch(void* const* d_in, const int* in_sizes, int n_in,
                              void* d_out, int out_size, void* d_ws, size_t ws_size,
                              hipStream_t stream) {
    const float* x         = (const float*)d_in[0];
    const float* centers   = (const float*)d_in[1];
    const float* log_sigma = (const float*)d_in[2];
    const float* cm        = (const float*)d_in[3];
    const float* clv       = (const float*)d_in[4];
    const float* bw        = (const float*)d_in[5];
    const float* eps       = (const float*)d_in[6];

    float* out = (float*)d_out;
    float* kl  = out + (size_t)B_SZ * OUT_F;   // output 1 (scalar), concatenated

    float* csum = (float*)d_ws;                // 32768 floats
    float* rbf  = csum + PAIRS;                // 4096*64 floats

    int S = in_sizes[6] / TOT;                 // = 1 for this problem

    // d_ws / d_out are 0xAA-poisoned before every call: zero the accumulators.
    hipMemsetAsync(csum, 0, PAIRS * sizeof(float), stream);
    hipMemsetAsync(kl, 0, sizeof(float), stream);

    k1_csum_kl<<<1024, 256, 0, stream>>>(cm, clv, eps, csum, kl, S);
    k2_rbf<<<B_SZ, 256, 0, stream>>>(x, centers, log_sigma, rbf);
    k3_out<<<(B_SZ / 64) * (OUT_F / 64), 256, 0, stream>>>(
        x, bw, rbf, csum, out, 1.0f / (float)S);
}

// Round 2
// 275.670 us; speedup vs baseline: 1.1819x; 1.1819x over previous
//
#include <hip/hip_runtime.h>
#include <hip/hip_bf16.h>

#define B_SZ  4096
#define IN_F  512
#define OUT_F 512
#define NC    64
#define PAIRS (OUT_F * NC)        // 32768
#define TOT   (IN_F * OUT_F * NC) // 16.8M
#define KCH   64                  // k1 i-chunks
#define ILEN  (IN_F / KCH)        // 8
#define KTOT  (IN_F + NC)         // 576: combined GEMM K (x@W + rbf@csum^T)

typedef __attribute__((ext_vector_type(8))) short bf16x8;
typedef __attribute__((ext_vector_type(4))) float f32x4;

static __device__ inline unsigned short f2bf(float f) {
    __hip_bfloat16 h = __float2bfloat16(f);   // RNE
    return *(unsigned short*)&h;
}

// ---------------------------------------------------------------------------
// K1: partial c_sum over i-chunks (NO atomics -> plain stores to ws) + KL.
// Grid 2048 blocks (8/CU -> 100% occupancy), unroll 4 -> 12 float4 in flight.
// Pure HBM-bound: reads 201 MB, writes 8 MB.
// ---------------------------------------------------------------------------
__global__ __launch_bounds__(256)
void k1_partial_kl(const float* __restrict__ cm,
                   const float* __restrict__ clv,
                   const float* __restrict__ eps,
                   float* __restrict__ part,
                   float* __restrict__ kl_out,
                   int S) {
    int pb = blockIdx.x >> 6;            // 0..31 pair-block (1024 pairs)
    int ch = blockIdx.x & 63;            // 0..63 i-chunk
    int p4 = pb * 1024 + threadIdx.x * 4;
    float Sf = (float)S;

    float4 s = {0.f, 0.f, 0.f, 0.f};
    float klp = 0.f;

#pragma unroll 4
    for (int ii = 0; ii < ILEN; ++ii) {
        int i = ch * ILEN + ii;
        size_t idx = (size_t)i * PAIRS + p4;
        float4 m  = *(const float4*)(cm  + idx);
        float4 lv = *(const float4*)(clv + idx);
        float4 es = *(const float4*)(eps + idx);
        for (int si = 1; si < S; ++si) {
            float4 e2 = *(const float4*)(eps + (size_t)si * TOT + idx);
            es.x += e2.x; es.y += e2.y; es.z += e2.z; es.w += e2.w;
        }
        float e1x = __expf(0.5f * lv.x);
        float e1y = __expf(0.5f * lv.y);
        float e1z = __expf(0.5f * lv.z);
        float e1w = __expf(0.5f * lv.w);
        s.x += Sf * m.x + es.x * e1x;
        s.y += Sf * m.y + es.y * e1y;
        s.z += Sf * m.z + es.z * e1z;
        s.w += Sf * m.w + es.w * e1w;
        klp += (e1x*e1x + m.x*m.x - 1.f - lv.x);
        klp += (e1y*e1y + m.y*m.y - 1.f - lv.y);
        klp += (e1z*e1z + m.z*m.z - 1.f - lv.z);
        klp += (e1w*e1w + m.w*m.w - 1.f - lv.w);
    }

    *(float4*)(part + (size_t)ch * PAIRS + p4) = s;

    // KL: wave shuffle reduce -> LDS -> one atomic per block (2048 total)
    for (int off = 32; off; off >>= 1)
        klp += __shfl_down(klp, off, 64);
    __shared__ float wsum[4];
    if ((threadIdx.x & 63) == 0) wsum[threadIdx.x >> 6] = klp;
    __syncthreads();
    if (threadIdx.x == 0)
        atomicAdd(kl_out, 0.5f * (wsum[0] + wsum[1] + wsum[2] + wsum[3]));
}

// ---------------------------------------------------------------------------
// K1r: reduce the 64 partials -> csum[o][n]*inv_S, written as bf16 directly
// into the combined-B matrix Wc^T[o][512+n]. 8 MB read, coalesced per chunk.
// ---------------------------------------------------------------------------
__global__ __launch_bounds__(256)
void k1_reduce(const float* __restrict__ part,
               unsigned short* __restrict__ wct,
               float inv_S) {
    int p4 = (blockIdx.x * 256 + threadIdx.x) * 4;
    float4 a = {0.f, 0.f, 0.f, 0.f};
#pragma unroll 8
    for (int ch = 0; ch < KCH; ++ch) {
        float4 v = *(const float4*)(part + (size_t)ch * PAIRS + p4);
        a.x += v.x; a.y += v.y; a.z += v.z; a.w += v.w;
    }
    int o = p4 >> 6, n = p4 & 63;
    ushort4 w;
    w.x = f2bf(a.x * inv_S);
    w.y = f2bf(a.y * inv_S);
    w.z = f2bf(a.z * inv_S);
    w.w = f2bf(a.w * inv_S);
    *(ushort4*)(wct + (size_t)o * KTOT + IN_F + n) = w;
}

// ---------------------------------------------------------------------------
// Kwt: transpose base_weight [k][o] f32 -> Wc^T[o][k] bf16 (cols 0..511).
// LDS 64x68 tile transpose; 64 blocks. ~1.5 MB traffic.
// ---------------------------------------------------------------------------
__global__ __launch_bounds__(256)
void k_wt(const float* __restrict__ bw, unsigned short* __restrict__ wct) {
    __shared__ float tile[64 * 68];     // stride 68: 16B-aligned rows, odd/17 bank step
    int bi = blockIdx.x >> 3;           // k-tile
    int bj = blockIdx.x & 7;            // o-tile
    int t = threadIdx.x;
    int cq = t & 15, rq = t >> 4;
#pragma unroll
    for (int rr = 0; rr < 4; ++rr) {
        int row = rq * 4 + rr;          // k-local
        float4 v = *(const float4*)(bw + (size_t)(bi * 64 + row) * OUT_F + bj * 64 + cq * 4);
        *(float4*)&tile[row * 68 + cq * 4] = v;
    }
    __syncthreads();
#pragma unroll
    for (int rr = 0; rr < 4; ++rr) {
        int orow = rq * 4 + rr;         // o-local
        ushort4 w;
        w.x = f2bf(tile[(cq * 4 + 0) * 68 + orow]);
        w.y = f2bf(tile[(cq * 4 + 1) * 68 + orow]);
        w.z = f2bf(tile[(cq * 4 + 2) * 68 + orow]);
        w.w = f2bf(tile[(cq * 4 + 3) * 68 + orow]);
        *(ushort4*)(wct + (size_t)(bj * 64 + orow) * KTOT + bi * 64 + cq * 4) = w;
    }
}

// ---------------------------------------------------------------------------
// K2: rbf[b][n] = exp(-dist_sq/(2*sigma^2+1e-8)), written as bf16.
// Block = 512 threads, 16 b-rows/block (256 blocks): thread (n=t>>3, c=t&7)
// register-caches its 64-float centers chunk ONCE (centers L2 traffic
// 512 MB -> 32 MB); x rows staged in 32 KB LDS, reads are 8-address
// broadcasts (conflict-free). shfl_xor over c reduces the 8 partials.
// ---------------------------------------------------------------------------
__global__ __launch_bounds__(512)
void k2_rbf(const float* __restrict__ x,
            const float* __restrict__ centers,
            const float* __restrict__ log_sigma,
            unsigned short* __restrict__ rbf) {
    __shared__ float4 xs4[2048];        // 16 rows x 512 floats = 32 KB
    int t = threadIdx.x;
    int b0 = blockIdx.x * 16;
    int n = t >> 3, c = t & 7;

    // register-cache centers[n][c*64 .. +63]
    float4 creg[16];
#pragma unroll
    for (int j = 0; j < 16; ++j)
        creg[j] = *(const float4*)(centers + (size_t)n * IN_F + c * 64 + j * 4);

    float sg  = __expf(log_sigma[n]);
    float inv = 1.f / (2.f * sg * sg + 1e-8f);

    // stage 16 contiguous x rows
    const float4* x4 = (const float4*)(x + (size_t)b0 * IN_F);
#pragma unroll
    for (int q = 0; q < 4; ++q)
        xs4[t + q * 512] = x4[t + q * 512];
    __syncthreads();

    for (int bi = 0; bi < 16; ++bi) {
        float d = 0.f;
#pragma unroll
        for (int j = 0; j < 16; ++j) {
            float4 xv = xs4[bi * 128 + c * 16 + j];
            float dx = xv.x - creg[j].x, dy = xv.y - creg[j].y;
            float dz = xv.z - creg[j].z, dw = xv.w - creg[j].w;
            d += dx*dx + dy*dy + dz*dz + dw*dw;
        }
        d += __shfl_xor(d, 1, 64);
        d += __shfl_xor(d, 2, 64);
        d += __shfl_xor(d, 4, 64);
        if (c == 0)
            rbf[(size_t)(b0 + bi) * NC + n] = f2bf(__expf(-d * inv));
    }
}

// ---------------------------------------------------------------------------
// K3: out = [x | rbf](bf16) @ Wc^T  via mfma_f32_16x16x32_bf16.
// 64x64 tile, 256 thr (4 waves x 16-row strips x 4 N-frags), BK=32,
// LDS row stride 40 bf16 (80 B: 16B-aligned b128 frags, 2-way max aliasing).
// x converted f32->bf16 inline during staging. Grid 512 = 2 blocks/CU.
// ---------------------------------------------------------------------------
__global__ __launch_bounds__(256)
void k3_mfma(const float* __restrict__ x,
             const unsigned short* __restrict__ rbf,
             const unsigned short* __restrict__ wct,
             float* __restrict__ out) {
    __shared__ __align__(16) unsigned short As[64 * 40];
    __shared__ __align__(16) unsigned short Bs[64 * 40];
    int t = threadIdx.x;
    int bm = blockIdx.x >> 3, bn = blockIdx.x & 7;
    int b0 = bm * 64, o0 = bn * 64;
    int r = t >> 2, ks = t & 3;          // staging: row 0..63, k-seg(8) 0..3
    int lane = t & 63, wv = t >> 6;      // compute: wave strip
    int fm = lane & 15, kg = lane >> 4;  // fragment row / k-group

    f32x4 acc[4] = {{0,0,0,0},{0,0,0,0},{0,0,0,0},{0,0,0,0}};
    const int soff = r * 40 + ks * 8;
    const int aoff = (wv * 16 + fm) * 40 + kg * 8;

    // ---- K 0..511: A from x (inline f32->bf16) ----
    for (int it = 0; it < 16; ++it) {
        int k0 = it * 32;
        float4 xa = *(const float4*)(x + (size_t)(b0 + r) * IN_F + k0 + ks * 8);
        float4 xb = *(const float4*)(x + (size_t)(b0 + r) * IN_F + k0 + ks * 8 + 4);
        ushort4 w0 = *(const ushort4*)(wct + (size_t)(o0 + r) * KTOT + k0 + ks * 8);
        ushort4 w1 = *(const ushort4*)(wct + (size_t)(o0 + r) * KTOT + k0 + ks * 8 + 4);
        __syncthreads();
        ushort4 a0 = {f2bf(xa.x), f2bf(xa.y), f2bf(xa.z), f2bf(xa.w)};
        ushort4 a1 = {f2bf(xb.x), f2bf(xb.y), f2bf(xb.z), f2bf(xb.w)};
        *(ushort4*)&As[soff]     = a0;
        *(ushort4*)&As[soff + 4] = a1;
        *(ushort4*)&Bs[soff]     = w0;
        *(ushort4*)&Bs[soff + 4] = w1;
        __syncthreads();
        bf16x8 af = *(bf16x8*)&As[aoff];
#pragma unroll
        for (int nf = 0; nf < 4; ++nf) {
            bf16x8 bfr = *(bf16x8*)&Bs[(nf * 16 + fm) * 40 + kg * 8];
            acc[nf] = __builtin_amdgcn_mfma_f32_16x16x32_bf16(af, bfr, acc[nf], 0, 0, 0);
        }
    }

    // ---- K 512..575: A from rbf (already bf16) ----
    for (int it = 0; it < 2; ++it) {
        int k0 = it * 32;
        ushort4 r0 = *(const ushort4*)(rbf + (size_t)(b0 + r) * NC + k0 + ks * 8);
        ushort4 r1 = *(const ushort4*)(rbf + (size_t)(b0 + r) * NC + k0 + ks * 8 + 4);
        ushort4 w0 = *(const ushort4*)(wct + (size_t)(o0 + r) * KTOT + IN_F + k0 + ks * 8);
        ushort4 w1 = *(const ushort4*)(wct + (size_t)(o0 + r) * KTOT + IN_F + k0 + ks * 8 + 4);
        __syncthreads();
        *(ushort4*)&As[soff]     = r0;
        *(ushort4*)&As[soff + 4] = r1;
        *(ushort4*)&Bs[soff]     = w0;
        *(ushort4*)&Bs[soff + 4] = w1;
        __syncthreads();
        bf16x8 af = *(bf16x8*)&As[aoff];
#pragma unroll
        for (int nf = 0; nf < 4; ++nf) {
            bf16x8 bfr = *(bf16x8*)&Bs[(nf * 16 + fm) * 40 + kg * 8];
            acc[nf] = __builtin_amdgcn_mfma_f32_16x16x32_bf16(af, bfr, acc[nf], 0, 0, 0);
        }
    }

    // epilogue: C/D layout col=lane&15, row=(lane>>4)*4+reg
#pragma unroll
    for (int nf = 0; nf < 4; ++nf)
#pragma unroll
        for (int rr = 0; rr < 4; ++rr)
            out[(size_t)(b0 + wv * 16 + kg * 4 + rr) * OUT_F + o0 + nf * 16 + fm] = acc[nf][rr];
}

// ---------------------------------------------------------------------------
extern "C" void kernel_launch(void* const* d_in, const int* in_sizes, int n_in,
                              void* d_out, int out_size, void* d_ws, size_t ws_size,
                              hipStream_t stream) {
    const float* x         = (const float*)d_in[0];
    const float* centers   = (const float*)d_in[1];
    const float* log_sigma = (const float*)d_in[2];
    const float* cm        = (const float*)d_in[3];
    const float* clv       = (const float*)d_in[4];
    const float* bw        = (const float*)d_in[5];
    const float* eps       = (const float*)d_in[6];

    float* out = (float*)d_out;
    float* kl  = out + (size_t)B_SZ * OUT_F;

    // ws: [part 8MB][WcT 576KB bf16][rbf 512KB bf16]  (~9.1 MB total)
    float* part = (float*)d_ws;
    unsigned short* wct = (unsigned short*)(part + (size_t)KCH * PAIRS);
    unsigned short* rbf = wct + (size_t)OUT_F * KTOT;

    int S = in_sizes[6] / TOT;   // = 1

    hipMemsetAsync(kl, 0, sizeof(float), stream);   // KL accumulator

    k1_partial_kl<<<2048, 256, 0, stream>>>(cm, clv, eps, part, kl, S);
    k1_reduce<<<PAIRS / 1024, 256, 0, stream>>>(part, wct, 1.0f / (float)S);
    k_wt<<<64, 256, 0, stream>>>(bw, wct);
    k2_rbf<<<B_SZ / 16, 512, 0, stream>>>(x, centers, log_sigma, rbf);
    k3_mfma<<<(B_SZ / 64) * (OUT_F / 64), 256, 0, stream>>>(x, rbf, wct, out);
}

// Round 3
// 264.829 us; speedup vs baseline: 1.2303x; 1.0409x over previous
//
#include <hip/hip_runtime.h>
#include <hip/hip_bf16.h>

#define B_SZ  4096
#define IN_F  512
#define OUT_F 512
#define NC    64
#define PAIRS 32768               // OUT_F * NC
#define TOT   (IN_F * PAIRS)      // 16.8M
#define KTOT  (IN_F + NC)         // 576: combined GEMM K
#define RCH   64                  // k1 row-chunks (8 rows each)

typedef __attribute__((ext_vector_type(8))) short bf16x8;
typedef __attribute__((ext_vector_type(4))) float f32x4;

static __device__ inline unsigned short f2bf(float f) {
    __hip_bfloat16 h = __float2bfloat16(f);   // RNE
    return *(unsigned short*)&h;
}

// ---------------------------------------------------------------------------
// K1: partial c_sum + kl partials. 512 blocks x 1024 threads.
// Block (pb, rc): pair-slice pb*4096 (16 KB contiguous per row per array),
// rows rc*8..+8. 12 float4 loads in flight (unroll 4). No atomics.
// ---------------------------------------------------------------------------
__global__ __launch_bounds__(1024)
void k1_partial(const float* __restrict__ cm,
                const float* __restrict__ clv,
                const float* __restrict__ eps,
                float* __restrict__ part,
                float* __restrict__ klpart,
                int S) {
    int pb = blockIdx.x & 7;
    int rc = blockIdx.x >> 3;            // 0..63
    int p4 = pb * 4096 + threadIdx.x * 4;
    float Sf = (float)S;
    float4 s = {0.f, 0.f, 0.f, 0.f};
    float klp = 0.f;

#pragma unroll 4
    for (int ii = 0; ii < 8; ++ii) {
        size_t idx = (size_t)(rc * 8 + ii) * PAIRS + p4;
        float4 m  = *(const float4*)(cm  + idx);
        float4 lv = *(const float4*)(clv + idx);
        float4 es = *(const float4*)(eps + idx);
        for (int si = 1; si < S; ++si) {
            float4 e2 = *(const float4*)(eps + (size_t)si * TOT + idx);
            es.x += e2.x; es.y += e2.y; es.z += e2.z; es.w += e2.w;
        }
        float e1x = __expf(0.5f * lv.x);
        float e1y = __expf(0.5f * lv.y);
        float e1z = __expf(0.5f * lv.z);
        float e1w = __expf(0.5f * lv.w);
        s.x += Sf * m.x + es.x * e1x;
        s.y += Sf * m.y + es.y * e1y;
        s.z += Sf * m.z + es.z * e1z;
        s.w += Sf * m.w + es.w * e1w;
        klp += (e1x*e1x + m.x*m.x - 1.f - lv.x);
        klp += (e1y*e1y + m.y*m.y - 1.f - lv.y);
        klp += (e1z*e1z + m.z*m.z - 1.f - lv.z);
        klp += (e1w*e1w + m.w*m.w - 1.f - lv.w);
    }

    *(float4*)(part + (size_t)rc * PAIRS + p4) = s;

    // kl: 16-wave block reduce -> one plain store per block
    for (int off = 32; off; off >>= 1)
        klp += __shfl_down(klp, off, 64);
    __shared__ float wsum[16];
    if ((threadIdx.x & 63) == 0) wsum[threadIdx.x >> 6] = klp;
    __syncthreads();
    if (threadIdx.x == 0) {
        float t = 0.f;
#pragma unroll
        for (int i = 0; i < 16; ++i) t += wsum[i];
        klpart[blockIdx.x] = t;
    }
}

// ---------------------------------------------------------------------------
// K_mid: fused (a) csum reduce -> wct cols 512..575 [blocks 0..127],
//              (b) base_weight transpose -> wct cols 0..511 [blocks 128..191],
//              (c) kl final reduce [block 192].  No memsets needed.
// ---------------------------------------------------------------------------
__global__ __launch_bounds__(256)
void k_mid(const float* __restrict__ part,
           const float* __restrict__ klpart,
           const float* __restrict__ bw,
           unsigned short* __restrict__ wct,
           float* __restrict__ kl_out,
           float inv_S) {
    __shared__ float tile[64 * 68];
    __shared__ float wsum[4];
    int bid = blockIdx.x, t = threadIdx.x;

    if (bid < 128) {                       // csum reduce (32768 pairs)
        int p = bid * 256 + t;
        float a = 0.f;
#pragma unroll 8
        for (int r = 0; r < RCH; ++r)
            a += part[(size_t)r * PAIRS + p];
        int o = p >> 6, n = p & 63;
        wct[(size_t)o * KTOT + IN_F + n] = f2bf(a * inv_S);
    } else if (bid < 192) {                // W transpose, bf16
        int bb = bid - 128;
        int bi = bb >> 3, bj = bb & 7;
        int cq = t & 15, rq = t >> 4;
#pragma unroll
        for (int rr = 0; rr < 4; ++rr) {
            int row = rq * 4 + rr;
            float4 v = *(const float4*)(bw + (size_t)(bi * 64 + row) * OUT_F + bj * 64 + cq * 4);
            *(float4*)&tile[row * 68 + cq * 4] = v;
        }
        __syncthreads();
#pragma unroll
        for (int rr = 0; rr < 4; ++rr) {
            int orow = rq * 4 + rr;
            ushort4 w;
            w.x = f2bf(tile[(cq * 4 + 0) * 68 + orow]);
            w.y = f2bf(tile[(cq * 4 + 1) * 68 + orow]);
            w.z = f2bf(tile[(cq * 4 + 2) * 68 + orow]);
            w.w = f2bf(tile[(cq * 4 + 3) * 68 + orow]);
            *(ushort4*)(wct + (size_t)(bj * 64 + orow) * KTOT + bi * 64 + cq * 4) = w;
        }
    } else {                               // kl final: 512 partials
        float v = klpart[t] + klpart[t + 256];
        for (int off = 32; off; off >>= 1)
            v += __shfl_down(v, off, 64);
        if ((t & 63) == 0) wsum[t >> 6] = v;
        __syncthreads();
        if (t == 0)
            kl_out[0] = 0.5f * (wsum[0] + wsum[1] + wsum[2] + wsum[3]);
    }
}

// ---------------------------------------------------------------------------
// K2: rbf. 256 blocks x 512 thr (8 waves). Wave w owns i-chunk [w*64, w*64+64);
// lane n owns center n: centers chunk register-cached (64 VGPR). x values are
// wave-uniform -> scalar loads (readfirstlane-forced), NO LDS in the hot loop.
// Per-row partials kept in 16 regs; one barrier; cross-wave reduce via LDS.
// ---------------------------------------------------------------------------
__global__ __launch_bounds__(512)
void k2_rbf(const float* __restrict__ x,
            const float* __restrict__ centers,
            const float* __restrict__ log_sigma,
            unsigned short* __restrict__ rbf) {
    __shared__ float red[16][8][64];       // [row][wave][center] = 32 KB
    int t = threadIdx.x;
    int n = t & 63;
    int wu = __builtin_amdgcn_readfirstlane(t >> 6);   // wave id, SGPR-uniform
    int b0 = blockIdx.x * 16;

    // register-cache centers[n][wu*64 .. +64)
    float creg[64];
#pragma unroll
    for (int q = 0; q < 16; ++q) {
        float4 v = *(const float4*)(centers + (size_t)n * IN_F + wu * 64 + q * 4);
        creg[q * 4 + 0] = v.x; creg[q * 4 + 1] = v.y;
        creg[q * 4 + 2] = v.z; creg[q * 4 + 3] = v.w;
    }

    float dacc[16];
#pragma unroll
    for (int bi = 0; bi < 16; ++bi) {
        const float* xr = x + (size_t)(b0 + bi) * IN_F + wu * 64;  // uniform
        float d0 = 0.f, d1 = 0.f, d2 = 0.f, d3 = 0.f;
#pragma unroll
        for (int j = 0; j < 64; j += 4) {
            float t0 = xr[j + 0] - creg[j + 0];
            float t1 = xr[j + 1] - creg[j + 1];
            float t2 = xr[j + 2] - creg[j + 2];
            float t3 = xr[j + 3] - creg[j + 3];
            d0 = fmaf(t0, t0, d0); d1 = fmaf(t1, t1, d1);
            d2 = fmaf(t2, t2, d2); d3 = fmaf(t3, t3, d3);
        }
        dacc[bi] = (d0 + d1) + (d2 + d3);
    }

#pragma unroll
    for (int bi = 0; bi < 16; ++bi)
        red[bi][wu][n] = dacc[bi];
    __syncthreads();

    // 1024 (bi,n) results over 512 threads: 2 passes
#pragma unroll
    for (int pass = 0; pass < 2; ++pass) {
        int idx = pass * 512 + t;
        int bi = idx >> 6, nn = idx & 63;
        float s = 0.f;
#pragma unroll
        for (int w = 0; w < 8; ++w) s += red[bi][w][nn];
        float sg  = __expf(log_sigma[nn]);
        float inv = 1.f / (2.f * sg * sg + 1e-8f);
        rbf[(size_t)(b0 + bi) * NC + nn] = f2bf(__expf(-s * inv));
    }
}

// ---------------------------------------------------------------------------
// K3: out = [x | rbf](bf16) @ Wc^T via mfma_f32_16x16x32_bf16. Unchanged
// from round 2 (verified correct; ~64x64 tile, 256 thr, BK=32, stride 40).
// ---------------------------------------------------------------------------
__global__ __launch_bounds__(256)
void k3_mfma(const float* __restrict__ x,
             const unsigned short* __restrict__ rbf,
             const unsigned short* __restrict__ wct,
             float* __restrict__ out) {
    __shared__ __align__(16) unsigned short As[64 * 40];
    __shared__ __align__(16) unsigned short Bs[64 * 40];
    int t = threadIdx.x;
    int bm = blockIdx.x >> 3, bn = blockIdx.x & 7;
    int b0 = bm * 64, o0 = bn * 64;
    int r = t >> 2, ks = t & 3;
    int lane = t & 63, wv = t >> 6;
    int fm = lane & 15, kg = lane >> 4;

    f32x4 acc[4] = {{0,0,0,0},{0,0,0,0},{0,0,0,0},{0,0,0,0}};
    const int soff = r * 40 + ks * 8;
    const int aoff = (wv * 16 + fm) * 40 + kg * 8;

    for (int it = 0; it < 16; ++it) {
        int k0 = it * 32;
        float4 xa = *(const float4*)(x + (size_t)(b0 + r) * IN_F + k0 + ks * 8);
        float4 xb = *(const float4*)(x + (size_t)(b0 + r) * IN_F + k0 + ks * 8 + 4);
        ushort4 w0 = *(const ushort4*)(wct + (size_t)(o0 + r) * KTOT + k0 + ks * 8);
        ushort4 w1 = *(const ushort4*)(wct + (size_t)(o0 + r) * KTOT + k0 + ks * 8 + 4);
        __syncthreads();
        ushort4 a0 = {f2bf(xa.x), f2bf(xa.y), f2bf(xa.z), f2bf(xa.w)};
        ushort4 a1 = {f2bf(xb.x), f2bf(xb.y), f2bf(xb.z), f2bf(xb.w)};
        *(ushort4*)&As[soff]     = a0;
        *(ushort4*)&As[soff + 4] = a1;
        *(ushort4*)&Bs[soff]     = w0;
        *(ushort4*)&Bs[soff + 4] = w1;
        __syncthreads();
        bf16x8 af = *(bf16x8*)&As[aoff];
#pragma unroll
        for (int nf = 0; nf < 4; ++nf) {
            bf16x8 bfr = *(bf16x8*)&Bs[(nf * 16 + fm) * 40 + kg * 8];
            acc[nf] = __builtin_amdgcn_mfma_f32_16x16x32_bf16(af, bfr, acc[nf], 0, 0, 0);
        }
    }

    for (int it = 0; it < 2; ++it) {
        int k0 = it * 32;
        ushort4 r0 = *(const ushort4*)(rbf + (size_t)(b0 + r) * NC + k0 + ks * 8);
        ushort4 r1 = *(const ushort4*)(rbf + (size_t)(b0 + r) * NC + k0 + ks * 8 + 4);
        ushort4 w0 = *(const ushort4*)(wct + (size_t)(o0 + r) * KTOT + IN_F + k0 + ks * 8);
        ushort4 w1 = *(const ushort4*)(wct + (size_t)(o0 + r) * KTOT + IN_F + k0 + ks * 8 + 4);
        __syncthreads();
        *(ushort4*)&As[soff]     = r0;
        *(ushort4*)&As[soff + 4] = r1;
        *(ushort4*)&Bs[soff]     = w0;
        *(ushort4*)&Bs[soff + 4] = w1;
        __syncthreads();
        bf16x8 af = *(bf16x8*)&As[aoff];
#pragma unroll
        for (int nf = 0; nf < 4; ++nf) {
            bf16x8 bfr = *(bf16x8*)&Bs[(nf * 16 + fm) * 40 + kg * 8];
            acc[nf] = __builtin_amdgcn_mfma_f32_16x16x32_bf16(af, bfr, acc[nf], 0, 0, 0);
        }
    }

#pragma unroll
    for (int nf = 0; nf < 4; ++nf)
#pragma unroll
        for (int rr = 0; rr < 4; ++rr)
            out[(size_t)(b0 + wv * 16 + kg * 4 + rr) * OUT_F + o0 + nf * 16 + fm] = acc[nf][rr];
}

// ---------------------------------------------------------------------------
extern "C" void kernel_launch(void* const* d_in, const int* in_sizes, int n_in,
                              void* d_out, int out_size, void* d_ws, size_t ws_size,
                              hipStream_t stream) {
    const float* x         = (const float*)d_in[0];
    const float* centers   = (const float*)d_in[1];
    const float* log_sigma = (const float*)d_in[2];
    const float* cm        = (const float*)d_in[3];
    const float* clv       = (const float*)d_in[4];
    const float* bw        = (const float*)d_in[5];
    const float* eps       = (const float*)d_in[6];

    float* out = (float*)d_out;
    float* kl  = out + (size_t)B_SZ * OUT_F;

    // ws: [part 8MB][klpart 2KB][WcT 576KB bf16][rbf 512KB bf16]
    float* part   = (float*)d_ws;
    float* klpart = part + (size_t)RCH * PAIRS;
    unsigned short* wct = (unsigned short*)(klpart + 512);
    unsigned short* rbf = wct + (size_t)OUT_F * KTOT;

    int S = in_sizes[6] / TOT;   // = 1

    k1_partial<<<512, 1024, 0, stream>>>(cm, clv, eps, part, klpart, S);
    k_mid<<<193, 256, 0, stream>>>(part, klpart, bw, wct, kl, 1.0f / (float)S);
    k2_rbf<<<B_SZ / 16, 512, 0, stream>>>(x, centers, log_sigma, rbf);
    k3_mfma<<<(B_SZ / 64) * (OUT_F / 64), 256, 0, stream>>>(x, rbf, wct, out);
}

// Round 4
// 259.935 us; speedup vs baseline: 1.2534x; 1.0188x over previous
//
#include <hip/hip_runtime.h>
#include <hip/hip_bf16.h>

#define B_SZ  4096
#define IN_F  512
#define OUT_F 512
#define NC    64
#define PAIRS 32768               // OUT_F * NC
#define TOT   (IN_F * PAIRS)      // 16.8M
#define KTOT  (IN_F + NC)         // 576: combined GEMM K
#define RCH   64                  // k1 row-chunks (8 rows each)

typedef __attribute__((ext_vector_type(8))) short bf16x8;
typedef __attribute__((ext_vector_type(4))) float f32x4;

static __device__ inline unsigned short f2bf(float f) {
    __hip_bfloat16 h = __float2bfloat16(f);   // RNE
    return *(unsigned short*)&h;
}

// ---------------------------------------------------------------------------
// K1: partial c_sum + kl. Grid 1024 = 16 pair-slices x 64 row-chunks, 512 thr.
// FORCED MLP: all 24 float4 loads (8 rows x {cm,clv,eps}) issued into explicit
// register arrays BEFORE any compute (two-phase). Prior rounds' VGPR=20..40
// prove the compiler was serializing to ~2 loads in flight; this round targets
// VGPR ~140 and >=12 outstanding loads/wave. Discriminates compiler-
// serialization theory (-> ~40us) vs fabric-read-ceiling theory (-> ~70us).
// ---------------------------------------------------------------------------
__global__ __launch_bounds__(512)
void k1_partial(const float* __restrict__ cm,
                const float* __restrict__ clv,
                const float* __restrict__ eps,
                float* __restrict__ part,
                float* __restrict__ klpart,
                int S) {
    int pb = blockIdx.x & 15;            // pair-slice: 2048 pairs (8 KB/row)
    int rc = blockIdx.x >> 4;            // row-chunk: rows rc*8..+8
    int p4 = pb * 2048 + (threadIdx.x << 2);
    size_t base = (size_t)(rc * 8) * PAIRS + p4;
    float Sf = (float)S;

    float4 M[8], LV[8], ES[8];
#pragma unroll
    for (int ii = 0; ii < 8; ++ii)
        M[ii] = *(const float4*)(cm + base + (size_t)ii * PAIRS);
#pragma unroll
    for (int ii = 0; ii < 8; ++ii)
        LV[ii] = *(const float4*)(clv + base + (size_t)ii * PAIRS);
#pragma unroll
    for (int ii = 0; ii < 8; ++ii)
        ES[ii] = *(const float4*)(eps + base + (size_t)ii * PAIRS);
    for (int si = 1; si < S; ++si)       // dead for S==1
#pragma unroll
        for (int ii = 0; ii < 8; ++ii) {
            float4 e = *(const float4*)(eps + (size_t)si * TOT + base + (size_t)ii * PAIRS);
            ES[ii].x += e.x; ES[ii].y += e.y; ES[ii].z += e.z; ES[ii].w += e.w;
        }

    float4 s = {0.f, 0.f, 0.f, 0.f};
    float klp = 0.f;
#pragma unroll
    for (int ii = 0; ii < 8; ++ii) {
        float e1x = __expf(0.5f * LV[ii].x);
        float e1y = __expf(0.5f * LV[ii].y);
        float e1z = __expf(0.5f * LV[ii].z);
        float e1w = __expf(0.5f * LV[ii].w);
        s.x += Sf * M[ii].x + ES[ii].x * e1x;
        s.y += Sf * M[ii].y + ES[ii].y * e1y;
        s.z += Sf * M[ii].z + ES[ii].z * e1z;
        s.w += Sf * M[ii].w + ES[ii].w * e1w;
        klp += (e1x*e1x + M[ii].x*M[ii].x - 1.f - LV[ii].x);
        klp += (e1y*e1y + M[ii].y*M[ii].y - 1.f - LV[ii].y);
        klp += (e1z*e1z + M[ii].z*M[ii].z - 1.f - LV[ii].z);
        klp += (e1w*e1w + M[ii].w*M[ii].w - 1.f - LV[ii].w);
    }

    *(float4*)(part + (size_t)rc * PAIRS + p4) = s;

    // kl: 8-wave block reduce -> one plain store per block
    for (int off = 32; off; off >>= 1)
        klp += __shfl_down(klp, off, 64);
    __shared__ float wsum[8];
    if ((threadIdx.x & 63) == 0) wsum[threadIdx.x >> 6] = klp;
    __syncthreads();
    if (threadIdx.x == 0) {
        float t = 0.f;
#pragma unroll
        for (int i = 0; i < 8; ++i) t += wsum[i];
        klpart[blockIdx.x] = t;
    }
}

// ---------------------------------------------------------------------------
// K_mid: one 385-block x 512-thr dispatch fusing:
//   blocks   0..255 : rbf (wave=i-chunk, lane=center, regs-cached centers)
//   blocks 256..319 : csum reduce (64 chunks) -> wct cols 512..575 (bf16)
//   blocks 320..383 : base_weight transpose -> wct cols 0..511 (bf16)
//   block  384      : kl final reduce
// ---------------------------------------------------------------------------
__global__ __launch_bounds__(512)
void k_mid(const float* __restrict__ x,
           const float* __restrict__ centers,
           const float* __restrict__ log_sigma,
           const float* __restrict__ part,
           const float* __restrict__ klpart,
           const float* __restrict__ bw,
           unsigned short* __restrict__ rbf,
           unsigned short* __restrict__ wct,
           float* __restrict__ kl_out,
           float inv_S) {
    __shared__ float shbuf[16 * 8 * 64];   // 32 KB, aliased per branch
    int bid = blockIdx.x, t = threadIdx.x;

    if (bid < 256) {
        // ---- rbf ----
        float (*red)[8][64] = (float (*)[8][64])shbuf;
        int n = t & 63;
        int wu = __builtin_amdgcn_readfirstlane(t >> 6);
        int b0 = bid * 16;

        float creg[64];
#pragma unroll
        for (int q = 0; q < 16; ++q) {
            float4 v = *(const float4*)(centers + (size_t)n * IN_F + wu * 64 + q * 4);
            creg[q * 4 + 0] = v.x; creg[q * 4 + 1] = v.y;
            creg[q * 4 + 2] = v.z; creg[q * 4 + 3] = v.w;
        }

        float dacc[16];
#pragma unroll
        for (int bi = 0; bi < 16; ++bi) {
            const float* xr = x + (size_t)(b0 + bi) * IN_F + wu * 64;
            float d0 = 0.f, d1 = 0.f, d2 = 0.f, d3 = 0.f;
#pragma unroll
            for (int j = 0; j < 64; j += 4) {
                float t0 = xr[j + 0] - creg[j + 0];
                float t1 = xr[j + 1] - creg[j + 1];
                float t2 = xr[j + 2] - creg[j + 2];
                float t3 = xr[j + 3] - creg[j + 3];
                d0 = fmaf(t0, t0, d0); d1 = fmaf(t1, t1, d1);
                d2 = fmaf(t2, t2, d2); d3 = fmaf(t3, t3, d3);
            }
            dacc[bi] = (d0 + d1) + (d2 + d3);
        }
#pragma unroll
        for (int bi = 0; bi < 16; ++bi)
            red[bi][wu][n] = dacc[bi];
        __syncthreads();
#pragma unroll
        for (int pass = 0; pass < 2; ++pass) {
            int idx = pass * 512 + t;
            int bi = idx >> 6, nn = idx & 63;
            float ssum = 0.f;
#pragma unroll
            for (int w = 0; w < 8; ++w) ssum += red[bi][w][nn];
            float sg  = __expf(log_sigma[nn]);
            float inv = 1.f / (2.f * sg * sg + 1e-8f);
            rbf[(size_t)(b0 + bi) * NC + nn] = f2bf(__expf(-ssum * inv));
        }
    } else if (bid < 320) {
        // ---- csum reduce: 64 blocks x 512 pairs ----
        int p = (bid - 256) * 512 + t;
        float a0 = 0.f, a1 = 0.f, a2 = 0.f, a3 = 0.f;
#pragma unroll
        for (int r = 0; r < RCH; r += 4) {
            a0 += part[(size_t)(r + 0) * PAIRS + p];
            a1 += part[(size_t)(r + 1) * PAIRS + p];
            a2 += part[(size_t)(r + 2) * PAIRS + p];
            a3 += part[(size_t)(r + 3) * PAIRS + p];
        }
        int o = p >> 6, n = p & 63;
        wct[(size_t)o * KTOT + IN_F + n] = f2bf(((a0 + a1) + (a2 + a3)) * inv_S);
    } else if (bid < 384) {
        // ---- W transpose (all 512 threads, 2 rows each) ----
        float* tile = shbuf;               // 64 x 68
        int bb = bid - 320;
        int bi = bb >> 3, bj = bb & 7;
        int cq = t & 15, rq = t >> 4;      // rq 0..31
#pragma unroll
        for (int rr = 0; rr < 2; ++rr) {
            int row = rq * 2 + rr;
            float4 v = *(const float4*)(bw + (size_t)(bi * 64 + row) * OUT_F + bj * 64 + cq * 4);
            *(float4*)&tile[row * 68 + cq * 4] = v;
        }
        __syncthreads();
#pragma unroll
        for (int rr = 0; rr < 2; ++rr) {
            int orow = rq * 2 + rr;
            ushort4 w;
            w.x = f2bf(tile[(cq * 4 + 0) * 68 + orow]);
            w.y = f2bf(tile[(cq * 4 + 1) * 68 + orow]);
            w.z = f2bf(tile[(cq * 4 + 2) * 68 + orow]);
            w.w = f2bf(tile[(cq * 4 + 3) * 68 + orow]);
            *(ushort4*)(wct + (size_t)(bj * 64 + orow) * KTOT + bi * 64 + cq * 4) = w;
        }
    } else {
        // ---- kl final: 1024 partials ----
        float v = klpart[t] + klpart[t + 512];
        for (int off = 32; off; off >>= 1)
            v += __shfl_down(v, off, 64);
        float* wsum = shbuf;
        if ((t & 63) == 0) wsum[t >> 6] = v;
        __syncthreads();
        if (t == 0) {
            float s = 0.f;
#pragma unroll
            for (int i = 0; i < 8; ++i) s += wsum[i];
            kl_out[0] = 0.5f * s;
        }
    }
}

// ---------------------------------------------------------------------------
// K3: out = [x | rbf](bf16) @ Wc^T via mfma_f32_16x16x32_bf16.
// 64x64 tile, 256 thr, BK=32, LDS stride 40. Unchanged (verified correct).
// ---------------------------------------------------------------------------
__global__ __launch_bounds__(256)
void k3_mfma(const float* __restrict__ x,
             const unsigned short* __restrict__ rbf,
             const unsigned short* __restrict__ wct,
             float* __restrict__ out) {
    __shared__ __align__(16) unsigned short As[64 * 40];
    __shared__ __align__(16) unsigned short Bs[64 * 40];
    int t = threadIdx.x;
    int bm = blockIdx.x >> 3, bn = blockIdx.x & 7;
    int b0 = bm * 64, o0 = bn * 64;
    int r = t >> 2, ks = t & 3;
    int lane = t & 63, wv = t >> 6;
    int fm = lane & 15, kg = lane >> 4;

    f32x4 acc[4] = {{0,0,0,0},{0,0,0,0},{0,0,0,0},{0,0,0,0}};
    const int soff = r * 40 + ks * 8;
    const int aoff = (wv * 16 + fm) * 40 + kg * 8;

    for (int it = 0; it < 16; ++it) {
        int k0 = it * 32;
        float4 xa = *(const float4*)(x + (size_t)(b0 + r) * IN_F + k0 + ks * 8);
        float4 xb = *(const float4*)(x + (size_t)(b0 + r) * IN_F + k0 + ks * 8 + 4);
        ushort4 w0 = *(const ushort4*)(wct + (size_t)(o0 + r) * KTOT + k0 + ks * 8);
        ushort4 w1 = *(const ushort4*)(wct + (size_t)(o0 + r) * KTOT + k0 + ks * 8 + 4);
        __syncthreads();
        ushort4 a0 = {f2bf(xa.x), f2bf(xa.y), f2bf(xa.z), f2bf(xa.w)};
        ushort4 a1 = {f2bf(xb.x), f2bf(xb.y), f2bf(xb.z), f2bf(xb.w)};
        *(ushort4*)&As[soff]     = a0;
        *(ushort4*)&As[soff + 4] = a1;
        *(ushort4*)&Bs[soff]     = w0;
        *(ushort4*)&Bs[soff + 4] = w1;
        __syncthreads();
        bf16x8 af = *(bf16x8*)&As[aoff];
#pragma unroll
        for (int nf = 0; nf < 4; ++nf) {
            bf16x8 bfr = *(bf16x8*)&Bs[(nf * 16 + fm) * 40 + kg * 8];
            acc[nf] = __builtin_amdgcn_mfma_f32_16x16x32_bf16(af, bfr, acc[nf], 0, 0, 0);
        }
    }

    for (int it = 0; it < 2; ++it) {
        int k0 = it * 32;
        ushort4 r0 = *(const ushort4*)(rbf + (size_t)(b0 + r) * NC + k0 + ks * 8);
        ushort4 r1 = *(const ushort4*)(rbf + (size_t)(b0 + r) * NC + k0 + ks * 8 + 4);
        ushort4 w0 = *(const ushort4*)(wct + (size_t)(o0 + r) * KTOT + IN_F + k0 + ks * 8);
        ushort4 w1 = *(const ushort4*)(wct + (size_t)(o0 + r) * KTOT + IN_F + k0 + ks * 8 + 4);
        __syncthreads();
        *(ushort4*)&As[soff]     = r0;
        *(ushort4*)&As[soff + 4] = r1;
        *(ushort4*)&Bs[soff]     = w0;
        *(ushort4*)&Bs[soff + 4] = w1;
        __syncthreads();
        bf16x8 af = *(bf16x8*)&As[aoff];
#pragma unroll
        for (int nf = 0; nf < 4; ++nf) {
            bf16x8 bfr = *(bf16x8*)&Bs[(nf * 16 + fm) * 40 + kg * 8];
            acc[nf] = __builtin_amdgcn_mfma_f32_16x16x32_bf16(af, bfr, acc[nf], 0, 0, 0);
        }
    }

#pragma unroll
    for (int nf = 0; nf < 4; ++nf)
#pragma unroll
        for (int rr = 0; rr < 4; ++rr)
            out[(size_t)(b0 + wv * 16 + kg * 4 + rr) * OUT_F + o0 + nf * 16 + fm] = acc[nf][rr];
}

// ---------------------------------------------------------------------------
extern "C" void kernel_launch(void* const* d_in, const int* in_sizes, int n_in,
                              void* d_out, int out_size, void* d_ws, size_t ws_size,
                              hipStream_t stream) {
    const float* x         = (const float*)d_in[0];
    const float* centers   = (const float*)d_in[1];
    const float* log_sigma = (const float*)d_in[2];
    const float* cm        = (const float*)d_in[3];
    const float* clv       = (const float*)d_in[4];
    const float* bw        = (const float*)d_in[5];
    const float* eps       = (const float*)d_in[6];

    float* out = (float*)d_out;
    float* kl  = out + (size_t)B_SZ * OUT_F;

    // ws: [part 8MB][klpart 4KB][WcT 576KB bf16][rbf 512KB bf16]
    float* part   = (float*)d_ws;
    float* klpart = part + (size_t)RCH * PAIRS;
    unsigned short* wct = (unsigned short*)(klpart + 1024);
    unsigned short* rbf = wct + (size_t)OUT_F * KTOT;

    int S = in_sizes[6] / TOT;   // = 1

    k1_partial<<<1024, 512, 0, stream>>>(cm, clv, eps, part, klpart, S);
    k_mid<<<385, 512, 0, stream>>>(x, centers, log_sigma, part, klpart, bw,
                                   rbf, wct, kl, 1.0f / (float)S);
    k3_mfma<<<(B_SZ / 64) * (OUT_F / 64), 256, 0, stream>>>(x, rbf, wct, out);
}